// Round 1
// baseline (1025.686 us; speedup 1.0000x reference)
//
#include <hip/hip_runtime.h>

typedef _Float16 half8 __attribute__((ext_vector_type(8)));
typedef float f32x4 __attribute__((ext_vector_type(4)));

#define DIM 256
#define NE 1024
#define NROWS 131072
#define DECAY 0.99f
#define ONE_MINUS 0.01f
#define EPS 1e-5f

// output offsets (floats) in d_out, concatenated in reference return order
#define OFF_Q    0u
#define OFF_DIFF 33554432u
#define OFF_IND  33554433u
#define OFF_NEMB 33685505u
#define OFF_NCS  33947649u
#define OFF_NEA  33948673u

// ---------------- K0: codebook prep ----------------
// embed is [256][1024] fp32. Produce:
//   bt_hi/bt_lo: [1024][256] f16 split planes (B^T layout, contiguous k)
//   embT:        [1024][256] fp32 (for exact quantize gather)
//   sqh:         [1024] fp32 = 0.5 * sum_d e[d][j]^2
__global__ void k0_prep(const float* __restrict__ embed,
                        _Float16* __restrict__ bt_hi, _Float16* __restrict__ bt_lo,
                        float* __restrict__ embT, float* __restrict__ sqh) {
    int j = blockIdx.x;        // 0..1023
    int d = threadIdx.x;       // 0..255
    float e = embed[d * NE + j];
    embT[j * DIM + d] = e;
    _Float16 h = (_Float16)e;
    _Float16 lo = (_Float16)(e - (float)h);
    bt_hi[j * DIM + d] = h;
    bt_lo[j * DIM + d] = lo;
    float s = e * e;
    for (int off = 32; off; off >>= 1) s += __shfl_down(s, off);
    __shared__ float wsum[4];
    if ((threadIdx.x & 63) == 0) wsum[threadIdx.x >> 6] = s;
    __syncthreads();
    if (threadIdx.x == 0) sqh[j] = 0.5f * (wsum[0] + wsum[1] + wsum[2] + wsum[3]);
}

// ---------------- K1: distance GEMM + argmin + quantize + diff + histogram ----------------
// block = 256 threads (4 waves), 64 rows/block (16 rows/wave), sweep all 1024 codes.
__launch_bounds__(256, 2)
__global__ void k1_main(const float* __restrict__ input,
                        const _Float16* __restrict__ bt_hi,
                        const _Float16* __restrict__ bt_lo,
                        const float* __restrict__ embT,
                        const float* __restrict__ sqh,
                        float* __restrict__ out,
                        int* __restrict__ jint,
                        int* __restrict__ counts,
                        float* __restrict__ diffpart) {
    constexpr int BPAD = 264;            // 256 + 8 f16 pad -> conflict-free b128
    __shared__ _Float16 Bh[64 * BPAD];
    __shared__ _Float16 Bl[64 * BPAD];
    __shared__ float sq_s[NE];
    __shared__ float dred[4];

    const int tid = threadIdx.x;
    const int w  = tid >> 6;     // wave 0..3
    const int l  = tid & 63;     // lane
    const int lg = l >> 4;       // k-group (0..3)
    const int lr = l & 15;       // A-row / B-col within fragment
    const int m0 = blockIdx.x * 64;
    const int myrow = m0 + w * 16 + lr;

    for (int i = tid; i < NE; i += 256) sq_s[i] = sqh[i];

    // ---- load this lane's A data (one row, 64 floats) and split to f16 hi/lo ----
    half8 ah[8], al[8];
    {
        const float* arow = input + (size_t)myrow * DIM + lg * 8;
        #pragma unroll
        for (int ks = 0; ks < 8; ++ks) {
            f32x4 x0 = *(const f32x4*)(arow + ks * 32);
            f32x4 x1 = *(const f32x4*)(arow + ks * 32 + 4);
            half8 h, lo;
            #pragma unroll
            for (int i = 0; i < 4; ++i) {
                _Float16 h0 = (_Float16)x0[i];
                h[i] = h0; lo[i] = (_Float16)(x0[i] - (float)h0);
                _Float16 h1 = (_Float16)x1[i];
                h[4 + i] = h1; lo[4 + i] = (_Float16)(x1[i] - (float)h1);
            }
            ah[ks] = h; al[ks] = lo;
        }
    }

    float best_val[4];
    int   best_idx[4];
    #pragma unroll
    for (int r = 0; r < 4; ++r) { best_val[r] = 3.4e38f; best_idx[r] = 0; }

    #pragma unroll 1
    for (int chunk = 0; chunk < 16; ++chunk) {
        const int n0 = chunk * 64;
        __syncthreads();
        // stage B chunk (64 codes x 256 k, hi+lo) into LDS
        {
            int row = tid >> 2, seg = tid & 3;
            const _Float16* srcH = bt_hi + (size_t)(n0 + row) * DIM + seg * 64;
            const _Float16* srcL = bt_lo + (size_t)(n0 + row) * DIM + seg * 64;
            _Float16* dstH = Bh + row * BPAD + seg * 64;
            _Float16* dstL = Bl + row * BPAD + seg * 64;
            #pragma unroll
            for (int i = 0; i < 8; ++i) {
                *(half8*)(dstH + i * 8) = *(const half8*)(srcH + i * 8);
                *(half8*)(dstL + i * 8) = *(const half8*)(srcL + i * 8);
            }
        }
        __syncthreads();

        f32x4 acc[4];
        #pragma unroll
        for (int nf = 0; nf < 4; ++nf) acc[nf] = (f32x4){0.f, 0.f, 0.f, 0.f};

        #pragma unroll
        for (int ks = 0; ks < 8; ++ks) {
            half8 bh[4], bl[4];
            #pragma unroll
            for (int nf = 0; nf < 4; ++nf) {
                bh[nf] = *(const half8*)(Bh + (nf * 16 + lr) * BPAD + ks * 32 + lg * 8);
                bl[nf] = *(const half8*)(Bl + (nf * 16 + lr) * BPAD + ks * 32 + lg * 8);
            }
            #pragma unroll
            for (int nf = 0; nf < 4; ++nf) {
                acc[nf] = __builtin_amdgcn_mfma_f32_16x16x32_f16(ah[ks], bh[nf], acc[nf], 0, 0, 0);
                acc[nf] = __builtin_amdgcn_mfma_f32_16x16x32_f16(al[ks], bh[nf], acc[nf], 0, 0, 0);
                acc[nf] = __builtin_amdgcn_mfma_f32_16x16x32_f16(ah[ks], bl[nf], acc[nf], 0, 0, 0);
            }
        }

        // score = 0.5*||e||^2 - x.e ; running argmin (ascending col order -> first-min)
        #pragma unroll
        for (int nf = 0; nf < 4; ++nf) {
            int col = n0 + nf * 16 + lr;
            float sq = sq_s[col];
            #pragma unroll
            for (int r = 0; r < 4; ++r) {
                float v = sq - acc[nf][r];
                if (v < best_val[r]) { best_val[r] = v; best_idx[r] = col; }
            }
        }
    }

    // ---- cross-lane argmin within each 16-lane group (rows lg*4+r) ----
    #pragma unroll
    for (int r = 0; r < 4; ++r) {
        float v = best_val[r]; int ix = best_idx[r];
        #pragma unroll
        for (int off = 1; off < 16; off <<= 1) {
            float ov = __shfl_xor(v, off);
            int   oi = __shfl_xor(ix, off);
            if (ov < v || (ov == v && oi < ix)) { v = ov; ix = oi; }
        }
        best_val[r] = v; best_idx[r] = ix;
    }

    if (lr == 0) {
        #pragma unroll
        for (int r = 0; r < 4; ++r) {
            int row = m0 + w * 16 + lg * 4 + r;
            int j = best_idx[r];
            out[OFF_IND + row] = (float)j;
            jint[row] = j;
            atomicAdd(&counts[j], 1);
        }
    }

    // ---- fetch the winning code index for THIS lane's A-row (row lr of the wave) ----
    int jb[4];
    #pragma unroll
    for (int r = 0; r < 4; ++r) jb[r] = __shfl(best_idx[r], (lr >> 2) * 16);
    int rsel = lr & 3;
    int jm = jb[0];
    if (rsel == 1) jm = jb[1];
    else if (rsel == 2) jm = jb[2];
    else if (rsel == 3) jm = jb[3];

    // ---- quantize gather/write + diff partial ----
    float dsum = 0.f;
    const float* qrow = embT + (size_t)jm * DIM + lg * 8;
    float* qout = out + OFF_Q + (size_t)myrow * DIM + lg * 8;
    #pragma unroll
    for (int ks = 0; ks < 8; ++ks) {
        f32x4 q0 = *(const f32x4*)(qrow + ks * 32);
        f32x4 q1 = *(const f32x4*)(qrow + ks * 32 + 4);
        *(f32x4*)(qout + ks * 32) = q0;
        *(f32x4*)(qout + ks * 32 + 4) = q1;
        #pragma unroll
        for (int i = 0; i < 4; ++i) {
            float x0 = (float)ah[ks][i] + (float)al[ks][i];
            float x1 = (float)ah[ks][4 + i] + (float)al[ks][4 + i];
            float d0 = q0[i] - x0, d1 = q1[i] - x1;
            dsum += d0 * d0 + d1 * d1;
        }
    }
    for (int off = 32; off; off >>= 1) dsum += __shfl_down(dsum, off);
    if (l == 0) dred[w] = dsum;
    __syncthreads();
    if (tid == 0) diffpart[blockIdx.x] = dred[0] + dred[1] + dred[2] + dred[3];
}

// ---------------- K2: scan + EMA scalars + diff finalize (1 block, 1024 thr) ----------------
__global__ void k2_small(const float* __restrict__ cluster_size,
                         const int* __restrict__ counts,
                         const float* __restrict__ diffpart,
                         float* __restrict__ out,
                         int* __restrict__ offsets,
                         float* __restrict__ cs_ws) {
    __shared__ float sf[1024];
    __shared__ int   si[1024];
    int t = threadIdx.x;
    int cnt = counts[t];
    float ncs = cluster_size[t] * DECAY + ONE_MINUS * (float)cnt;
    out[OFF_NCS + t] = ncs;

    sf[t] = ncs; __syncthreads();
    for (int s = 512; s; s >>= 1) { if (t < s) sf[t] += sf[t + s]; __syncthreads(); }
    float n = sf[0];
    float csv = (ncs + EPS) / (n + (float)NE * EPS) * n;
    cs_ws[t] = csv;

    si[t] = cnt; __syncthreads();
    for (int off = 1; off < 1024; off <<= 1) {
        int v = (t >= off) ? si[t - off] : 0;
        __syncthreads();
        si[t] += v;
        __syncthreads();
    }
    offsets[t] = si[t] - cnt;  // exclusive prefix

    float dp = diffpart[t] + diffpart[t + 1024];
    __syncthreads();
    sf[t] = dp; __syncthreads();
    for (int s = 512; s; s >>= 1) { if (t < s) sf[t] += sf[t + s]; __syncthreads(); }
    if (t == 0) out[OFF_DIFF] = sf[0] / 33554432.0f;
}

// ---------------- K3: scatter row ids into per-code buckets ----------------
__global__ void k3_scatter(const int* __restrict__ jint,
                           const int* __restrict__ offsets,
                           int* __restrict__ cursors,
                           int* __restrict__ list) {
    int r = blockIdx.x * 256 + threadIdx.x;
    int j = jint[r];
    int pos = atomicAdd(&cursors[j], 1);
    list[offsets[j] + pos] = r;
}

// ---------------- K4: per-code segment sum + EMA outputs ----------------
__global__ void k4_final(const float* __restrict__ input,
                         const float* __restrict__ embed_avg,
                         const int* __restrict__ counts,
                         const int* __restrict__ offsets,
                         const int* __restrict__ list,
                         const float* __restrict__ cs_ws,
                         float* __restrict__ out) {
    __shared__ int lrows[2048];
    int j = blockIdx.x;
    int d = threadIdx.x;
    int cnt = counts[j];
    int off = offsets[j];
    float sum = 0.f;
    for (int base = 0; base < cnt; base += 2048) {
        int m = min(cnt - base, 2048);
        __syncthreads();
        for (int i = d; i < m; i += 256) lrows[i] = list[off + base + i];
        __syncthreads();
        #pragma unroll 4
        for (int i = 0; i < m; ++i) {
            sum += input[(size_t)lrows[i] * DIM + d];
        }
    }
    float na = embed_avg[d * NE + j] * DECAY + ONE_MINUS * sum;
    out[OFF_NEA + (size_t)d * NE + j] = na;
    out[OFF_NEMB + (size_t)d * NE + j] = na / cs_ws[j];
}

extern "C" void kernel_launch(void* const* d_in, const int* in_sizes, int n_in,
                              void* d_out, int out_size, void* d_ws, size_t ws_size,
                              hipStream_t stream) {
    const float* input        = (const float*)d_in[0];
    const float* embed        = (const float*)d_in[1];
    const float* cluster_size = (const float*)d_in[2];
    const float* embed_avg    = (const float*)d_in[3];
    float* out = (float*)d_out;
    char* ws = (char*)d_ws;

    _Float16* bt_hi  = (_Float16*)(ws + 0);
    _Float16* bt_lo  = (_Float16*)(ws + 524288);
    float*    embT   = (float*)(ws + 1048576);
    float*    sqh    = (float*)(ws + 2097152);
    int*      counts = (int*)(ws + 2101248);
    int*      offsets= (int*)(ws + 2105344);
    int*      cursors= (int*)(ws + 2113536);
    int*      jint   = (int*)(ws + 2117632);
    int*      list   = (int*)(ws + 2641920);
    float*    diffpart = (float*)(ws + 3166208);
    float*    cs_ws  = (float*)(ws + 3174400);

    hipMemsetAsync(counts, 0, 4096, stream);
    hipMemsetAsync(cursors, 0, 4096, stream);

    k0_prep<<<1024, 256, 0, stream>>>(embed, bt_hi, bt_lo, embT, sqh);
    k1_main<<<2048, 256, 0, stream>>>(input, bt_hi, bt_lo, embT, sqh, out, jint, counts, diffpart);
    k2_small<<<1, 1024, 0, stream>>>(cluster_size, counts, diffpart, out, offsets, cs_ws);
    k3_scatter<<<512, 256, 0, stream>>>(jint, offsets, cursors, list);
    k4_final<<<1024, 256, 0, stream>>>(input, embed_avg, counts, offsets, list, cs_ws, out);
}